// Round 12
// baseline (94.245 us; speedup 1.0000x reference)
//
#include <hip/hip_runtime.h>
#include <math.h>

#define NN   8
#define INCH 32
#define INN  50000
#define OUTC 64
#define OUTN 8192
#define DD   32
#define CC   256            // NN*INCH
#define NPL  8              // c-planes
#define PLDW ((size_t)INN * 16)   // dwords per plane: 50000 rows x 16 dwords(64B) = 3.2 MB

#define PREP_REPS 4   // DIAGNOSTIC: multiply pure work to surface in rocprof top-5
#define GATH_REPS 3   // DIAGNOSTIC

__device__ __forceinline__ unsigned f2bf_u(float f) {
  unsigned u = __float_as_uint(f);
  return (u + 0x7FFFu + ((u >> 16) & 1u)) >> 16;   // round-nearest-even
}

// dword convention: yTc plane p, row j, pos q (0..15) holds bf16 pair (c_lo, c_lo+128),
// c_lo = p*16 + q.

// Kernel 1: x*nf -> yTc (bf16 pairs). DIAGNOSTIC: body repeated PREP_REPS x (idempotent).
__global__ __launch_bounds__(256) void prep_kernel(
    const float* __restrict__ x, const float* __restrict__ nf, unsigned* __restrict__ yTc) {
  __shared__ float tile[CC][33];   // stride 33 words: <=2-way banks all phases
  const int t = threadIdx.x;
  const int j0 = blockIdx.x * 32;
  const int jmax = min(32, INN - j0);   // 50000 = 1562*32 + 16

  const int q  = t & 7;
  const int r0 = t >> 3;
  const int lane = t & 63;
  const int wave = t >> 6;

  for (int rep = 0; rep < PREP_REPS; ++rep) {
    asm volatile("" ::: "memory");   // defeat cross-rep CSE: genuinely re-execute
    if (q * 4 < jmax) {
      const float4 nv = *(const float4*)(nf + (size_t)r0 * INN + j0 + 4 * q);
      #pragma unroll
      for (int p = 0; p < 8; ++p) {
        const int c = (p << 5) + r0;
        const float4 xv = *(const float4*)(x + (size_t)c * INN + j0 + 4 * q);
        float4 pr;
        pr.x = xv.x * nv.x; pr.y = xv.y * nv.y; pr.z = xv.z * nv.z; pr.w = xv.w * nv.w;
        *(float4*)&tile[c][4 * q] = pr;   // bank (r0+4q)%32 -> <=2-way
      }
    }
    __syncthreads();

    #pragma unroll
    for (int r = 0; r < 8; ++r) {
      const int jl = wave * 8 + r;
      if (jl < jmax) {
        #pragma unroll
        for (int e = 0; e < 2; ++e) {
          const int clo = lane + 64 * e;                 // 0..127
          const unsigned lo = f2bf_u(tile[clo][jl]);     // bank (lane+jl)%32 -> 2-way
          const unsigned hi = f2bf_u(tile[clo + 128][jl]);
          const int pl  = clo >> 4;
          const int pos = clo & 15;
          yTc[(size_t)pl * PLDW + (size_t)(j0 + jl) * 16 + pos] = lo | (hi << 16);
        }
      }
    }
    __syncthreads();   // before next rep overwrites tile
  }
}

// Kernel 2: c-sliced gather (R11 structure). DIAGNOSTIC: reduction repeated GATH_REPS x.
__global__ __launch_bounds__(256, 8) void gather_kernel(
    const unsigned* __restrict__ yTc, const int* __restrict__ A, unsigned* __restrict__ red32) {
  __shared__ int Al[32 * 33];   // A[o0..o0+31][0..31], padded
  const int t = threadIdx.x;
  const int ck = blockIdx.x & 7;
  const int ob = blockIdx.x >> 3;   // 0..255
  const int o0 = ob * 32;

  #pragma unroll
  for (int k = 0; k < 4; ++k) {
    const int f = k * 256 + t;                      // 0..1023, coalesced
    Al[(f >> 5) * 33 + (f & 31)] = A[(size_t)o0 * DD + f];
  }
  __syncthreads();

  const unsigned* plane = yTc + (size_t)ck * PLDW;
  const int osub = t >> 3;          // 0..31
  const int cq   = (t >> 1) & 3;    // 0..3
  const int dh   = t & 1;           // 0..1

  for (int rep = 0; rep < GATH_REPS; ++rep) {
    asm volatile("" ::: "memory");   // defeat cross-rep CSE
    float l0 = -INFINITY, l1 = -INFINITY, l2 = -INFINITY, l3 = -INFINITY;
    float h0 = -INFINITY, h1 = -INFINITY, h2 = -INFINITY, h3 = -INFINITY;

    #pragma unroll 8
    for (int k = 0; k < 16; ++k) {
      const int d = 2 * k + dh;
      const int idx = Al[osub * 33 + d];   // conflict-free broadcast
      const uint4 v = *(const uint4*)(plane + (size_t)idx * 16 + cq * 4);  // 16x64B segs
      l0 = fmaxf(l0, __uint_as_float(v.x << 16));  h0 = fmaxf(h0, __uint_as_float(v.x & 0xffff0000u));
      l1 = fmaxf(l1, __uint_as_float(v.y << 16));  h1 = fmaxf(h1, __uint_as_float(v.y & 0xffff0000u));
      l2 = fmaxf(l2, __uint_as_float(v.z << 16));  h2 = fmaxf(h2, __uint_as_float(v.z & 0xffff0000u));
      l3 = fmaxf(l3, __uint_as_float(v.w << 16));  h3 = fmaxf(h3, __uint_as_float(v.w & 0xffff0000u));
    }
    // merge lane pairs (t, t^1)
    l0 = fmaxf(l0, __shfl_xor(l0, 1));  h0 = fmaxf(h0, __shfl_xor(h0, 1));
    l1 = fmaxf(l1, __shfl_xor(l1, 1));  h1 = fmaxf(h1, __shfl_xor(h1, 1));
    l2 = fmaxf(l2, __shfl_xor(l2, 1));  h2 = fmaxf(h2, __shfl_xor(h2, 1));
    l3 = fmaxf(l3, __shfl_xor(l3, 1));  h3 = fmaxf(h3, __shfl_xor(h3, 1));

    uint2 pk;
    if (dh == 0) {
      pk.x = (__float_as_uint(l0) >> 16) | (__float_as_uint(h0) & 0xffff0000u);
      pk.y = (__float_as_uint(l1) >> 16) | (__float_as_uint(h1) & 0xffff0000u);
    } else {
      pk.x = (__float_as_uint(l2) >> 16) | (__float_as_uint(h2) & 0xffff0000u);
      pk.y = (__float_as_uint(l3) >> 16) | (__float_as_uint(h3) & 0xffff0000u);
    }
    *(uint2*)(red32 + (size_t)(o0 + osub) * 128 + ck * 16 + cq * 4 + dh * 2) = pk;
  }
}

// Kernel 3 (unchanged): out[n,k,o] = sum_i red[o][n*32+i]*ft[i][k] + bias[k][o]
__global__ __launch_bounds__(256) void out_kernel(
    const unsigned* __restrict__ red32, const float* __restrict__ ft,
    const float* __restrict__ bias, float* __restrict__ out) {
  __shared__ float rtile[64][65];   // pad 65 -> <=2-way
  __shared__ float ftl[32][64];
  const int t = threadIdx.x;
  const int lane = t & 63;
  const int wave = t >> 6;
  const int np = blockIdx.x >> 7;   // 0..3
  const int ot = blockIdx.x & 127;  // 0..127
  const int o0 = ot * 64;
  const int hi = np >> 1;
  const int sb = (np & 1) * 64;

  #pragma unroll
  for (int q = 0; q < 8; ++q) {
    const int idx = q * 256 + t;
    ftl[idx >> 6][idx & 63] = ft[idx];
  }
  #pragma unroll
  for (int i = 0; i < 2; ++i) {
    const int r = (t >> 3) + 32 * i;
    const int g = t & 7;
    const unsigned* src = red32 + (size_t)(o0 + r) * 128 + sb + g * 8;
    const uint4 v0 = *(const uint4*)(src);
    const uint4 v1 = *(const uint4*)(src + 4);
    const unsigned w[8] = {v0.x, v0.y, v0.z, v0.w, v1.x, v1.y, v1.z, v1.w};
    float* dst = &rtile[r][g * 8];
    #pragma unroll
    for (int u = 0; u < 8; ++u)
      dst[u] = __uint_as_float(hi ? (w[u] & 0xffff0000u) : (w[u] << 16));
  }
  __syncthreads();

  const int n  = np * 2 + (wave & 1);
  const int kh = (wave >> 1) * 32;
  const int cb = (wave & 1) * 32;

  float rv[32];
  #pragma unroll
  for (int i = 0; i < 32; ++i) rv[i] = rtile[lane][cb + i];   // 2-way

  float acc[32];
  #pragma unroll
  for (int kk = 0; kk < 32; ++kk) acc[kk] = 0.f;
  #pragma unroll
  for (int i = 0; i < 32; ++i) {
    #pragma unroll
    for (int kk = 0; kk < 32; ++kk)
      acc[kk] += rv[i] * ftl[i][kh + kk];   // uniform addr -> broadcast
  }

  float* op = out + (size_t)n * OUTC * OUTN + o0 + lane;
  const float* bp = bias + o0 + lane;
  #pragma unroll
  for (int kk = 0; kk < 32; ++kk) {
    const int k = kh + kk;
    op[(size_t)k * OUTN] = acc[kk] + bp[(size_t)k * OUTN];   // 256B-contiguous stores
  }
}

extern "C" void kernel_launch(void* const* d_in, const int* in_sizes, int n_in,
                              void* d_out, int out_size, void* d_ws, size_t ws_size,
                              hipStream_t stream) {
  const float* x    = (const float*)d_in[0];
  const float* nf   = (const float*)d_in[1];
  const float* ft   = (const float*)d_in[2];
  const float* bias = (const float*)d_in[3];
  const int*   A    = (const int*)d_in[4];
  float* out = (float*)d_out;

  unsigned* yTc   = (unsigned*)d_ws;                           // 8 x 3.2 MB = 25.6 MB
  unsigned* red32 = (unsigned*)((char*)d_ws + NPL * PLDW * 4); // 8192*128*4 = 4.2 MB

  hipLaunchKernelGGL(prep_kernel,   dim3((INN + 31) / 32),   dim3(256), 0, stream, x, nf, yTc);
  hipLaunchKernelGGL(gather_kernel, dim3((OUTN / 32) * NPL), dim3(256), 0, stream, yTc, A, red32);
  hipLaunchKernelGGL(out_kernel,    dim3(512),               dim3(256), 0, stream, red32, ft, bias, out);
}

// Round 13
// 49.498 us; speedup vs baseline: 1.9040x; 1.9040x over previous
//
#include <hip/hip_runtime.h>
#include <math.h>

#define NN   8
#define INCH 32
#define INN  50000
#define OUTC 64
#define OUTN 8192
#define DD   32
#define CC   256            // NN*INCH
#define NPL  8              // c-planes
#define PLDW ((size_t)INN * 16)   // dwords per plane: 50000 rows x 16 dwords(64B) = 3.2 MB

__device__ __forceinline__ unsigned f2bf_u(float f) {
  unsigned u = __float_as_uint(f);
  return (u + 0x7FFFu + ((u >> 16) & 1u)) >> 16;   // round-nearest-even
}

// dword convention: yTc plane p, row j, pos q (0..15) holds bf16 pair (c_lo, c_lo+128),
// c_lo = p*16 + q.

// Kernel 1: x*nf -> yTc. Software-pipelined: two 16-j half-tiles; h1's global loads
// issue before h0's store phase -> read latency hides under LDS+stores.
__global__ __launch_bounds__(256) void prep_kernel(
    const float* __restrict__ x, const float* __restrict__ nf, unsigned* __restrict__ yTc) {
  __shared__ float tile[2][CC][17];   // 34 KB; stride 17 dwords: 2-way banks everywhere
  const int t = threadIdx.x;
  const int j0 = blockIdx.x * 32;
  const bool h1v = (INN - j0) > 16;   // last block (j0=49984) has exactly 16 j -> h0 only
  const int q  = t & 3;               // float4 within 16-j half
  const int r0 = t >> 2;              // 0..63
  const int lane = t & 63;
  const int wave = t >> 6;            // 0..3

  const float* nfrow = nf + (size_t)(r0 & 31) * INN + j0 + 4 * q;
  const float* xbase = x + (size_t)r0 * INN + j0 + 4 * q;

  // ---- P1(h0): 16 lanes-groups x 64B segments, fully coalesced
  {
    const float4 nv = *(const float4*)(nfrow);
    #pragma unroll
    for (int p = 0; p < 4; ++p) {
      const float4 xv = *(const float4*)(xbase + (size_t)(p * 64) * INN);
      float4 pr;
      pr.x = xv.x * nv.x; pr.y = xv.y * nv.y; pr.z = xv.z * nv.z; pr.w = xv.w * nv.w;
      *(float4*)&tile[0][(p << 6) + r0][4 * q] = pr;   // bank (17r0+4q)%32 -> 2-way
    }
  }
  __syncthreads();

  // ---- P1(h1) issue (loads in flight) + P2(h0) (LDS reads + stores run under them)
  if (h1v) {
    const float4 nv = *(const float4*)(nfrow + 16);
    #pragma unroll
    for (int p = 0; p < 4; ++p) {
      const float4 xv = *(const float4*)(xbase + (size_t)(p * 64) * INN + 16);
      float4 pr;
      pr.x = xv.x * nv.x; pr.y = xv.y * nv.y; pr.z = xv.z * nv.z; pr.w = xv.w * nv.w;
      *(float4*)&tile[1][(p << 6) + r0][4 * q] = pr;
    }
  }
  #pragma unroll
  for (int rr = 0; rr < 4; ++rr) {
    const int jl = wave * 4 + rr;                    // 0..15
    #pragma unroll
    for (int e = 0; e < 2; ++e) {
      const int clo = lane + 64 * e;                 // 0..127
      const unsigned lo = f2bf_u(tile[0][clo][jl]);  // bank (17lane+jl)%32 -> 2-way
      const unsigned hi = f2bf_u(tile[0][clo + 128][jl]);
      yTc[(size_t)(clo >> 4) * PLDW + (size_t)(j0 + jl) * 16 + (clo & 15)] = lo | (hi << 16);
    }
  }
  __syncthreads();

  // ---- P2(h1)
  if (h1v) {
    #pragma unroll
    for (int rr = 0; rr < 4; ++rr) {
      const int jl = wave * 4 + rr;
      #pragma unroll
      for (int e = 0; e < 2; ++e) {
        const int clo = lane + 64 * e;
        const unsigned lo = f2bf_u(tile[1][clo][jl]);
        const unsigned hi = f2bf_u(tile[1][clo + 128][jl]);
        yTc[(size_t)(clo >> 4) * PLDW + (size_t)(j0 + 16 + jl) * 16 + (clo & 15)] = lo | (hi << 16);
      }
    }
  }
}

// Kernel 2 (R11, proven): c-sliced gather. 2048 blocks (plane=b%8, 32 o's), 8 blocks/CU.
__global__ __launch_bounds__(256, 8) void gather_kernel(
    const unsigned* __restrict__ yTc, const int* __restrict__ A, unsigned* __restrict__ red32) {
  __shared__ int Al[32 * 33];   // A[o0..o0+31][0..31], padded
  const int t = threadIdx.x;
  const int ck = blockIdx.x & 7;
  const int ob = blockIdx.x >> 3;   // 0..255
  const int o0 = ob * 32;

  #pragma unroll
  for (int k = 0; k < 4; ++k) {
    const int f = k * 256 + t;                      // 0..1023, coalesced
    Al[(f >> 5) * 33 + (f & 31)] = A[(size_t)o0 * DD + f];
  }
  __syncthreads();

  const unsigned* plane = yTc + (size_t)ck * PLDW;
  const int osub = t >> 3;          // 0..31
  const int cq   = (t >> 1) & 3;    // 0..3
  const int dh   = t & 1;           // 0..1

  float l0 = -INFINITY, l1 = -INFINITY, l2 = -INFINITY, l3 = -INFINITY;
  float h0 = -INFINITY, h1 = -INFINITY, h2 = -INFINITY, h3 = -INFINITY;

  #pragma unroll 8
  for (int k = 0; k < 16; ++k) {
    const int d = 2 * k + dh;
    const int idx = Al[osub * 33 + d];   // conflict-free broadcast
    const uint4 v = *(const uint4*)(plane + (size_t)idx * 16 + cq * 4);  // 16x64B segs/instr
    l0 = fmaxf(l0, __uint_as_float(v.x << 16));  h0 = fmaxf(h0, __uint_as_float(v.x & 0xffff0000u));
    l1 = fmaxf(l1, __uint_as_float(v.y << 16));  h1 = fmaxf(h1, __uint_as_float(v.y & 0xffff0000u));
    l2 = fmaxf(l2, __uint_as_float(v.z << 16));  h2 = fmaxf(h2, __uint_as_float(v.z & 0xffff0000u));
    l3 = fmaxf(l3, __uint_as_float(v.w << 16));  h3 = fmaxf(h3, __uint_as_float(v.w & 0xffff0000u));
  }
  // merge lane pairs (t, t^1)
  l0 = fmaxf(l0, __shfl_xor(l0, 1));  h0 = fmaxf(h0, __shfl_xor(h0, 1));
  l1 = fmaxf(l1, __shfl_xor(l1, 1));  h1 = fmaxf(h1, __shfl_xor(h1, 1));
  l2 = fmaxf(l2, __shfl_xor(l2, 1));  h2 = fmaxf(h2, __shfl_xor(h2, 1));
  l3 = fmaxf(l3, __shfl_xor(l3, 1));  h3 = fmaxf(h3, __shfl_xor(h3, 1));

  uint2 pk;
  if (dh == 0) {
    pk.x = (__float_as_uint(l0) >> 16) | (__float_as_uint(h0) & 0xffff0000u);
    pk.y = (__float_as_uint(l1) >> 16) | (__float_as_uint(h1) & 0xffff0000u);
  } else {
    pk.x = (__float_as_uint(l2) >> 16) | (__float_as_uint(h2) & 0xffff0000u);
    pk.y = (__float_as_uint(l3) >> 16) | (__float_as_uint(h3) & 0xffff0000u);
  }
  *(uint2*)(red32 + (size_t)(o0 + osub) * 128 + ck * 16 + cq * 4 + dh * 2) = pk;
}

// Kernel 3 (proven): out[n,k,o] = sum_i red[o][n*32+i]*ft[i][k] + bias[k][o]
__global__ __launch_bounds__(256) void out_kernel(
    const unsigned* __restrict__ red32, const float* __restrict__ ft,
    const float* __restrict__ bias, float* __restrict__ out) {
  __shared__ float rtile[64][65];   // pad 65 -> <=2-way
  __shared__ float ftl[32][64];
  const int t = threadIdx.x;
  const int lane = t & 63;
  const int wave = t >> 6;
  const int np = blockIdx.x >> 7;   // 0..3
  const int ot = blockIdx.x & 127;  // 0..127
  const int o0 = ot * 64;
  const int hi = np >> 1;
  const int sb = (np & 1) * 64;

  #pragma unroll
  for (int q = 0; q < 8; ++q) {
    const int idx = q * 256 + t;
    ftl[idx >> 6][idx & 63] = ft[idx];
  }
  #pragma unroll
  for (int i = 0; i < 2; ++i) {
    const int r = (t >> 3) + 32 * i;
    const int g = t & 7;
    const unsigned* src = red32 + (size_t)(o0 + r) * 128 + sb + g * 8;
    const uint4 v0 = *(const uint4*)(src);
    const uint4 v1 = *(const uint4*)(src + 4);
    const unsigned w[8] = {v0.x, v0.y, v0.z, v0.w, v1.x, v1.y, v1.z, v1.w};
    float* dst = &rtile[r][g * 8];
    #pragma unroll
    for (int u = 0; u < 8; ++u)
      dst[u] = __uint_as_float(hi ? (w[u] & 0xffff0000u) : (w[u] << 16));
  }
  __syncthreads();

  const int n  = np * 2 + (wave & 1);
  const int kh = (wave >> 1) * 32;
  const int cb = (wave & 1) * 32;

  float rv[32];
  #pragma unroll
  for (int i = 0; i < 32; ++i) rv[i] = rtile[lane][cb + i];   // 2-way

  float acc[32];
  #pragma unroll
  for (int kk = 0; kk < 32; ++kk) acc[kk] = 0.f;
  #pragma unroll
  for (int i = 0; i < 32; ++i) {
    #pragma unroll
    for (int kk = 0; kk < 32; ++kk)
      acc[kk] += rv[i] * ftl[i][kh + kk];   // uniform addr -> broadcast
  }

  float* op = out + (size_t)n * OUTC * OUTN + o0 + lane;
  const float* bp = bias + o0 + lane;
  #pragma unroll
  for (int kk = 0; kk < 32; ++kk) {
    const int k = kh + kk;
    op[(size_t)k * OUTN] = acc[kk] + bp[(size_t)k * OUTN];   // 256B-contiguous stores
  }
}

extern "C" void kernel_launch(void* const* d_in, const int* in_sizes, int n_in,
                              void* d_out, int out_size, void* d_ws, size_t ws_size,
                              hipStream_t stream) {
  const float* x    = (const float*)d_in[0];
  const float* nf   = (const float*)d_in[1];
  const float* ft   = (const float*)d_in[2];
  const float* bias = (const float*)d_in[3];
  const int*   A    = (const int*)d_in[4];
  float* out = (float*)d_out;

  unsigned* yTc   = (unsigned*)d_ws;                           // 8 x 3.2 MB = 25.6 MB
  unsigned* red32 = (unsigned*)((char*)d_ws + NPL * PLDW * 4); // 8192*128*4 = 4.2 MB

  hipLaunchKernelGGL(prep_kernel,   dim3((INN + 31) / 32),   dim3(256), 0, stream, x, nf, yTc);
  hipLaunchKernelGGL(gather_kernel, dim3((OUTN / 32) * NPL), dim3(256), 0, stream, yTc, A, red32);
  hipLaunchKernelGGL(out_kernel,    dim3(512),               dim3(256), 0, stream, red32, ft, bias, out);
}

// Round 14
// 46.356 us; speedup vs baseline: 2.0330x; 1.0678x over previous
//
#include <hip/hip_runtime.h>
#include <math.h>

#define NN   8
#define INCH 32
#define INN  50000
#define OUTC 64
#define OUTN 8192
#define DD   32
#define CC   256            // NN*INCH
#define NPL  8              // c-planes
#define PLDW ((size_t)INN * 16)   // dwords per plane: 50000 rows x 16 dwords(64B) = 3.2 MB

typedef unsigned short ushortT;

__device__ __forceinline__ unsigned f2bf_u(float f) {
  unsigned u = __float_as_uint(f);
  return (u + 0x7FFFu + ((u >> 16) & 1u)) >> 16;   // round-nearest-even
}

// dword convention: yTc plane p, row j, pos q (0..15) holds bf16 pair (c_lo, c_lo+128),
// c_lo = p*16 + q.

// Kernel 1: x*nf -> yTc. DRAM-friendly reads: 64-col j-window, 16 lanes/row ->
// 4 rows x 256B contiguous per wave-instr, 16 independent passes (MLP).
__global__ __launch_bounds__(256) void prep_kernel(
    const float* __restrict__ x, const float* __restrict__ nf, unsigned* __restrict__ yTc) {
  __shared__ ushortT tile[CC][70];   // 35 KB; stride 70 ushorts (35 dwords, odd) -> <=2-way
  const int t = threadIdx.x;
  const int j0 = blockIdx.x * 64;
  const int jmax = min(64, INN - j0);   // 50000 = 781*64 + 16 -> last block 16
  const int m  = t & 15;    // float4-col within window
  const int r0 = t >> 4;    // 0..15
  const int lane = t & 63;
  const int wave = t >> 6;

  if (4 * m < jmax) {
    // nf row = c&31: p even -> r0, p odd -> r0+16 (two hoisted loads)
    const float4 nv0 = *(const float4*)(nf + (size_t)r0 * INN + j0 + 4 * m);
    const float4 nv1 = *(const float4*)(nf + (size_t)(r0 + 16) * INN + j0 + 4 * m);
    #pragma unroll 8
    for (int p = 0; p < 16; ++p) {
      const int c = (p << 4) + r0;
      const float4 xv = *(const float4*)(x + (size_t)c * INN + j0 + 4 * m);  // 256B/row seg
      const float4 nv = (p & 1) ? nv1 : nv0;
      // two 4B-aligned dword writes; banks (35c+2m+s)%32, rw-parity mixed -> <=2-way
      *(unsigned*)&tile[c][4 * m]     = f2bf_u(xv.x * nv.x) | (f2bf_u(xv.y * nv.y) << 16);
      *(unsigned*)&tile[c][4 * m + 2] = f2bf_u(xv.z * nv.z) | (f2bf_u(xv.w * nv.w) << 16);
    }
  }
  __syncthreads();

  // store (proven shape): per instr lane l -> clo=l+64e; 4 planes x 64B segments
  #pragma unroll
  for (int rr = 0; rr < 16; ++rr) {
    const int jl = wave * 16 + rr;
    if (jl < jmax) {
      #pragma unroll
      for (int e = 0; e < 2; ++e) {
        const int clo = lane + 64 * e;               // 0..127
        // ushort reads bank (3*clo + (jl>>1))%32 -> uniform 2-way (free)
        const unsigned lo = tile[clo][jl];
        const unsigned hi = tile[clo + 128][jl];
        yTc[(size_t)(clo >> 4) * PLDW + (size_t)(j0 + jl) * 16 + (clo & 15)] = lo | (hi << 16);
      }
    }
  }
}

// Kernel 2 (R11, proven): c-sliced gather. 2048 blocks (plane=b%8, 32 o's), 8 blocks/CU.
__global__ __launch_bounds__(256, 8) void gather_kernel(
    const unsigned* __restrict__ yTc, const int* __restrict__ A, unsigned* __restrict__ red32) {
  __shared__ int Al[32 * 33];   // A[o0..o0+31][0..31], padded
  const int t = threadIdx.x;
  const int ck = blockIdx.x & 7;
  const int ob = blockIdx.x >> 3;   // 0..255
  const int o0 = ob * 32;

  #pragma unroll
  for (int k = 0; k < 4; ++k) {
    const int f = k * 256 + t;                      // 0..1023, coalesced
    Al[(f >> 5) * 33 + (f & 31)] = A[(size_t)o0 * DD + f];
  }
  __syncthreads();

  const unsigned* plane = yTc + (size_t)ck * PLDW;
  const int osub = t >> 3;          // 0..31
  const int cq   = (t >> 1) & 3;    // 0..3
  const int dh   = t & 1;           // 0..1

  float l0 = -INFINITY, l1 = -INFINITY, l2 = -INFINITY, l3 = -INFINITY;
  float h0 = -INFINITY, h1 = -INFINITY, h2 = -INFINITY, h3 = -INFINITY;

  #pragma unroll 8
  for (int k = 0; k < 16; ++k) {
    const int d = 2 * k + dh;
    const int idx = Al[osub * 33 + d];   // conflict-free broadcast
    const uint4 v = *(const uint4*)(plane + (size_t)idx * 16 + cq * 4);  // 16x64B segs/instr
    l0 = fmaxf(l0, __uint_as_float(v.x << 16));  h0 = fmaxf(h0, __uint_as_float(v.x & 0xffff0000u));
    l1 = fmaxf(l1, __uint_as_float(v.y << 16));  h1 = fmaxf(h1, __uint_as_float(v.y & 0xffff0000u));
    l2 = fmaxf(l2, __uint_as_float(v.z << 16));  h2 = fmaxf(h2, __uint_as_float(v.z & 0xffff0000u));
    l3 = fmaxf(l3, __uint_as_float(v.w << 16));  h3 = fmaxf(h3, __uint_as_float(v.w & 0xffff0000u));
  }
  // merge lane pairs (t, t^1)
  l0 = fmaxf(l0, __shfl_xor(l0, 1));  h0 = fmaxf(h0, __shfl_xor(h0, 1));
  l1 = fmaxf(l1, __shfl_xor(l1, 1));  h1 = fmaxf(h1, __shfl_xor(h1, 1));
  l2 = fmaxf(l2, __shfl_xor(l2, 1));  h2 = fmaxf(h2, __shfl_xor(h2, 1));
  l3 = fmaxf(l3, __shfl_xor(l3, 1));  h3 = fmaxf(h3, __shfl_xor(h3, 1));

  uint2 pk;
  if (dh == 0) {
    pk.x = (__float_as_uint(l0) >> 16) | (__float_as_uint(h0) & 0xffff0000u);
    pk.y = (__float_as_uint(l1) >> 16) | (__float_as_uint(h1) & 0xffff0000u);
  } else {
    pk.x = (__float_as_uint(l2) >> 16) | (__float_as_uint(h2) & 0xffff0000u);
    pk.y = (__float_as_uint(l3) >> 16) | (__float_as_uint(h3) & 0xffff0000u);
  }
  *(uint2*)(red32 + (size_t)(o0 + osub) * 128 + ck * 16 + cq * 4 + dh * 2) = pk;
}

// Kernel 3 (proven): out[n,k,o] = sum_i red[o][n*32+i]*ft[i][k] + bias[k][o]
__global__ __launch_bounds__(256) void out_kernel(
    const unsigned* __restrict__ red32, const float* __restrict__ ft,
    const float* __restrict__ bias, float* __restrict__ out) {
  __shared__ float rtile[64][65];   // pad 65 -> <=2-way
  __shared__ float ftl[32][64];
  const int t = threadIdx.x;
  const int lane = t & 63;
  const int wave = t >> 6;
  const int np = blockIdx.x >> 7;   // 0..3
  const int ot = blockIdx.x & 127;  // 0..127
  const int o0 = ot * 64;
  const int hi = np >> 1;
  const int sb = (np & 1) * 64;

  #pragma unroll
  for (int q = 0; q < 8; ++q) {
    const int idx = q * 256 + t;
    ftl[idx >> 6][idx & 63] = ft[idx];
  }
  #pragma unroll
  for (int i = 0; i < 2; ++i) {
    const int r = (t >> 3) + 32 * i;
    const int g = t & 7;
    const unsigned* src = red32 + (size_t)(o0 + r) * 128 + sb + g * 8;
    const uint4 v0 = *(const uint4*)(src);
    const uint4 v1 = *(const uint4*)(src + 4);
    const unsigned w[8] = {v0.x, v0.y, v0.z, v0.w, v1.x, v1.y, v1.z, v1.w};
    float* dst = &rtile[r][g * 8];
    #pragma unroll
    for (int u = 0; u < 8; ++u)
      dst[u] = __uint_as_float(hi ? (w[u] & 0xffff0000u) : (w[u] << 16));
  }
  __syncthreads();

  const int n  = np * 2 + (wave & 1);
  const int kh = (wave >> 1) * 32;
  const int cb = (wave & 1) * 32;

  float rv[32];
  #pragma unroll
  for (int i = 0; i < 32; ++i) rv[i] = rtile[lane][cb + i];   // 2-way

  float acc[32];
  #pragma unroll
  for (int kk = 0; kk < 32; ++kk) acc[kk] = 0.f;
  #pragma unroll
  for (int i = 0; i < 32; ++i) {
    #pragma unroll
    for (int kk = 0; kk < 32; ++kk)
      acc[kk] += rv[i] * ftl[i][kh + kk];   // uniform addr -> broadcast
  }

  float* op = out + (size_t)n * OUTC * OUTN + o0 + lane;
  const float* bp = bias + o0 + lane;
  #pragma unroll
  for (int kk = 0; kk < 32; ++kk) {
    const int k = kh + kk;
    op[(size_t)k * OUTN] = acc[kk] + bp[(size_t)k * OUTN];   // 256B-contiguous stores
  }
}

extern "C" void kernel_launch(void* const* d_in, const int* in_sizes, int n_in,
                              void* d_out, int out_size, void* d_ws, size_t ws_size,
                              hipStream_t stream) {
  const float* x    = (const float*)d_in[0];
  const float* nf   = (const float*)d_in[1];
  const float* ft   = (const float*)d_in[2];
  const float* bias = (const float*)d_in[3];
  const int*   A    = (const int*)d_in[4];
  float* out = (float*)d_out;

  unsigned* yTc   = (unsigned*)d_ws;                           // 8 x 3.2 MB = 25.6 MB
  unsigned* red32 = (unsigned*)((char*)d_ws + NPL * PLDW * 4); // 8192*128*4 = 4.2 MB

  hipLaunchKernelGGL(prep_kernel,   dim3((INN + 63) / 64),   dim3(256), 0, stream, x, nf, yTc);
  hipLaunchKernelGGL(gather_kernel, dim3((OUTN / 32) * NPL), dim3(256), 0, stream, yTc, A, red32);
  hipLaunchKernelGGL(out_kernel,    dim3(512),               dim3(256), 0, stream, red32, ft, bias, out);
}